// Round 1
// baseline (9.637 us; speedup 1.0000x reference)
//
#include <hip/hip_runtime.h>
#include <hip/hip_bf16.h>

// GraphSage_36550171689307
//
// Key observation: the reference's final op is
//     softmax(x @ wd5 + bd5, axis=-1)  with  (x @ wd5 + bd5).shape == [R1, 1]
// Softmax over a length-1 axis is identically 1.0 for any finite input.
// Therefore the entire upstream graph (gathers, diffusion GEMMs, dense MLP,
// l2-normalize) is dead code and the exact output is ones([1024, 1], f32).
//
// The kernel is deterministic, input-independent, and bit-exact.

__global__ void GraphSage_write_ones(float* __restrict__ out, int n) {
    int i = blockIdx.x * blockDim.x + threadIdx.x;
    if (i < n) out[i] = 1.0f;
}

extern "C" void kernel_launch(void* const* d_in, const int* in_sizes, int n_in,
                              void* d_out, int out_size, void* d_ws, size_t ws_size,
                              hipStream_t stream) {
    (void)d_in; (void)in_sizes; (void)n_in; (void)d_ws; (void)ws_size;
    float* out = (float*)d_out;
    const int n = out_size;               // expected 1024 (R1 x 1)
    const int block = 256;
    const int grid = (n + block - 1) / block;
    GraphSage_write_ones<<<grid, block, 0, stream>>>(out, n);
}